// Round 10
// baseline (675.630 us; speedup 1.0000x reference)
//
#include <hip/hip_runtime.h>
#include <math.h>

#define NB 8
#define NN 10000
#define NT 12
#define ND 16
#define NH 128
#define NE 160000
#define BN (NB * NN)  // 80000

typedef __attribute__((ext_vector_type(8))) short short8v;
typedef __attribute__((ext_vector_type(4))) float f32x4;
typedef unsigned short u16;

#define NL2E  -1.442695041f   // -log2(e)
#define N2L2E -2.885390082f   // -2*log2(e)

__device__ __forceinline__ u16 bf16_rn(float f) {
    unsigned int u = __float_as_uint(f);
    u += 0x7fffu + ((u >> 16) & 1u);
    return (u16)(u >> 16);
}
__device__ __forceinline__ float bf16f(u16 s) {
    return __uint_as_float((unsigned int)s << 16);
}
// trunc-hi + rn-lo split packed as (lo<<16)|hi
__device__ __forceinline__ unsigned int pack_split(float f) {
    unsigned int u = __float_as_uint(f);
    unsigned int hh = u >> 16;
    float rem = f - __uint_as_float(u & 0xffff0000u);
    unsigned int hl = bf16_rn(rem);
    return (hl << 16) | hh;
}

// ---------- prep: SCALED weight splits (exp2 gates) + CSR init --------------
__global__ void prep_w_k(const float* __restrict__ Whh, const float* __restrict__ Wih,
                         const float* __restrict__ g1w, const float* __restrict__ g2w,
                         u16* __restrict__ whh_hi,
                         u16* __restrict__ wih_hi2, u16* __restrict__ wih_lo2,
                         u16* __restrict__ g1hi, u16* __restrict__ g2hi,
                         float* __restrict__ deg, int* __restrict__ cnt, int* __restrict__ fill)
{
    int i = blockIdx.x * 256 + threadIdx.x;   // 65536 threads
    if (i < 512 * 128) {
        int j = i >> 7;
        float s = ((j >> 7) == 2) ? N2L2E : NL2E;
        whh_hi[i] = bf16_rn(s * Whh[i]);
    }
    if (i < 512 * 16) {
        int row = i >> 4, d = i & 15;
        float s = ((row >> 7) == 2) ? N2L2E : NL2E;
        float w = s * Wih[i];
        unsigned int u = __float_as_uint(w);
        u16 h = (u16)(u >> 16);
        u16 l = bf16_rn(w - __uint_as_float(u & 0xffff0000u));
        wih_hi2[row * 32 + d] = h;        // pairs with [x_hi; x_lo]
        wih_hi2[row * 32 + 16 + d] = h;
        wih_lo2[row * 32 + d] = l;        // pairs with [x_hi; 0]
        wih_lo2[row * 32 + 16 + d] = 0;
    }
    if (i < 128 * 128) {
        g1hi[i] = bf16_rn(g1w[i]);
        g2hi[i] = bf16_rn(g2w[i]);
    }
    if (i < NN) { deg[i] = 1.0f; cnt[i] = 0; fill[i] = 0; }   // 1.0 = self-loop
}

// ---------- LSTM v4b: swapped-operand MFMA (z^T), b64 plane writes ----------
// 512 thr (8 waves), 64 seqs/block, (512,2) spill-free. Thread owns
// seq = m*16+l15, j = j0+4*lg+r. Gates pre-scaled -> exp2 + paired rcp.
__global__ __launch_bounds__(512, 2) void lstm4b_k(
    const float* __restrict__ x,
    const u16* __restrict__ whh_hi,
    const u16* __restrict__ wih_hi2, const u16* __restrict__ wih_lo2,
    const float* __restrict__ bih, const float* __restrict__ bhh,
    u16* __restrict__ hhi_g, u16* __restrict__ hlo_g)
{
    __shared__ __align__(16) u16 Hhi[2][64][128];   // 32 KB
    __shared__ __align__(16) u16 Hlo[2][64][128];   // 32 KB
    __shared__ __align__(16) u16 Hx[2][64][40];     // 10 KB (80B rows)
    const int tid = threadIdx.x;
    const int lane = tid & 63;
    const int wid = tid >> 6;
    const int j0 = wid * 16;
    const int l15 = lane & 15;
    const int lg = lane >> 4;          // 0..3
    const long seq0 = (long)blockIdx.x * 64;
    const int swzr = (l15 & 7) << 3;   // XOR swizzle (16B granules), read+write
    const int xs_seq = tid >> 3;       // x staging: 8 threads/seq-row
    const int xd0 = (tid & 7) * 2;

    // B fragments in registers: Whh (scaled, 64 VGPR) + Wih hi/lo (32 VGPR)
    short8v Bh[4][4];                  // [kt][gate]
    short8v b1[4], b2[4];
    f32x4 bv4[4];                      // per-gate bias for the 4 owned j
#pragma unroll
    for (int kt = 0; kt < 4; ++kt)
#pragma unroll
        for (int g = 0; g < 4; ++g) {
            int row = g * NH + j0 + l15;
            Bh[kt][g] = *(const short8v*)(whh_hi + row * NH + kt * 32 + 8 * lg);
        }
#pragma unroll
    for (int g = 0; g < 4; ++g) {
        int row = g * NH + j0 + l15;
        b1[g] = *(const short8v*)(wih_hi2 + row * 32 + 8 * lg);
        b2[g] = *(const short8v*)(wih_lo2 + row * 32 + 8 * lg);
        const float sc = (g == 2) ? N2L2E : NL2E;
#pragma unroll
        for (int r = 0; r < 4; ++r) {
            int rw = g * NH + j0 + 4 * lg + r;
            bv4[g][r] = (bih[rw] + bhh[rw]) * sc;
        }
    }

    // stage x for t=0
    {
        float2 xv = *(const float2*)(x + ((seq0 + xs_seq) * NT + 0) * ND + xd0);
        unsigned int p0 = pack_split(xv.x), p1 = pack_split(xv.y);
        *(ushort2*)&Hx[0][xs_seq][xd0] = make_ushort2((u16)p0, (u16)p1);
        *(ushort2*)&Hx[0][xs_seq][16 + xd0] = make_ushort2((u16)(p0 >> 16), (u16)(p1 >> 16));
    }
    f32x4 c[4];
#pragma unroll
    for (int m = 0; m < 4; ++m) c[m] = (f32x4){0.f, 0.f, 0.f, 0.f};
    __syncthreads();

    for (int t = 0; t < NT; ++t) {
        const int cur = t & 1, nxt = cur ^ 1;
        float2 xv;
        if (t + 1 < NT)
            xv = *(const float2*)(x + ((seq0 + xs_seq) * NT + (t + 1)) * ND + xd0);

#pragma unroll
        for (int m = 0; m < 4; ++m) {
            const int sq = m * 16 + l15;
            short8v xa = *(const short8v*)&Hx[cur][sq][8 * lg];

            f32x4 acc[4];
#pragma unroll
            for (int g = 0; g < 4; ++g) acc[g] = bv4[g];

            if (t > 0) {
#pragma unroll
                for (int kt = 0; kt < 4; ++kt) {
                    const int kk = (kt * 32 + 8 * lg) ^ swzr;
                    short8v ah = *(const short8v*)&Hhi[cur][sq][kk];
                    short8v al = *(const short8v*)&Hlo[cur][sq][kk];
#pragma unroll
                    for (int g = 0; g < 4; ++g)   // A = W (regs), B = h (LDS)
                        acc[g] = __builtin_amdgcn_mfma_f32_16x16x32_bf16(Bh[kt][g], ah, acc[g], 0, 0, 0);
#pragma unroll
                    for (int g = 0; g < 4; ++g)
                        acc[g] = __builtin_amdgcn_mfma_f32_16x16x32_bf16(Bh[kt][g], al, acc[g], 0, 0, 0);
                }
            }
#pragma unroll
            for (int g = 0; g < 4; ++g)
                acc[g] = __builtin_amdgcn_mfma_f32_16x16x32_bf16(b1[g], xa, acc[g], 0, 0, 0);
#pragma unroll
            for (int g = 0; g < 4; ++g)
                acc[g] = __builtin_amdgcn_mfma_f32_16x16x32_bf16(b2[g], xa, acc[g], 0, 0, 0);

            // epilogue: thread owns seq = m*16+l15, j = j0+4lg+r
            unsigned int p[4];
#pragma unroll
            for (int r = 0; r < 4; ++r) {
                const float ui = exp2f(acc[0][r]);
                const float uf = exp2f(acc[1][r]);
                const float ug = exp2f(acc[2][r]);
                const float uo = exp2f(acc[3][r]);
                const float di = 1.f + ui, df = 1.f + uf;
                const float dg = 1.f + ug, dd = 1.f + uo;
                const float r0 = __builtin_amdgcn_rcpf(di * df);
                const float r1 = __builtin_amdgcn_rcpf(dg * dd);
                const float si = r0 * df;                   // sigmoid(i)
                const float sf = r0 * di;                   // sigmoid(f)
                const float tg = fmaf(2.f, r1 * dd, -1.f);  // tanh(g)
                const float so = r1 * dg;                   // sigmoid(o)
                const float cc = fmaf(sf, c[m][r], si * tg);
                c[m][r] = cc;
                const float uc = exp2f(cc * N2L2E);
                const float rc = __builtin_amdgcn_rcpf(1.f + uc);
                const float hv = fmaf(2.f, so * rc, -so);   // o * tanh(c)
                p[r] = pack_split(hv);
            }
            uint2 hiw, low;
            hiw.x = (p[0] & 0xffffu) | (p[1] << 16);
            hiw.y = (p[2] & 0xffffu) | (p[3] << 16);
            low.x = (p[0] >> 16) | (p[1] & 0xffff0000u);
            low.y = (p[2] >> 16) | (p[3] & 0xffff0000u);
            const int off = (j0 + 4 * lg) ^ swzr;  // 8B-aligned, conflict-free
            *(uint2*)&Hhi[nxt][sq][off] = hiw;
            *(uint2*)&Hlo[nxt][sq][off] = low;
        }

        if (t + 1 < NT) {
            unsigned int p0 = pack_split(xv.x), p1 = pack_split(xv.y);
            *(ushort2*)&Hx[nxt][xs_seq][xd0] = make_ushort2((u16)p0, (u16)p1);
            *(ushort2*)&Hx[nxt][xs_seq][16 + xd0] = make_ushort2((u16)(p0 >> 16), (u16)(p1 >> 16));
        }
        __syncthreads();
    }

    // copy-out (node-major rows n*8+b): final h is in buffer 0 (12 steps)
    for (int ci = tid; ci < 2048; ci += 512) {
        int plane = ci >> 10;
        int rem = ci & 1023;
        int s = rem >> 4, g16 = rem & 15;
        int sg = g16 ^ (s & 7);
        unsigned int sglob = (unsigned int)(seq0 + s);
        unsigned int b = sglob / NN;
        unsigned int n = sglob - b * NN;
        const uint4* src = (const uint4*)(plane ? &Hlo[0][s][sg * 8] : &Hhi[0][s][sg * 8]);
        uint4* dst = (uint4*)((plane ? hlo_g : hhi_g) + ((long)n * 8 + b) * NH + g16 * 8);
        *dst = *src;
    }
}

// ---------- GCN GEMM: out = A @ W^T, A split hi/lo, W bf16 (row-agnostic) ---
__global__ __launch_bounds__(512) void gemmx2_k(
    const u16* __restrict__ Ahi, const u16* __restrict__ Alo,
    const u16* __restrict__ Whi, float* __restrict__ out)
{
    const int tid = threadIdx.x;
    const int lane = tid & 63;
    const int wid = tid >> 6;
    const int j0 = wid * 16;
    const int l15 = lane & 15;
    const int lg = lane >> 4;
    const long row0 = (long)blockIdx.x * 64;

    short8v Bh[4];
#pragma unroll
    for (int kt = 0; kt < 4; ++kt)
        Bh[kt] = *(const short8v*)(Whi + (j0 + l15) * NH + kt * 32 + 8 * lg);

#pragma unroll
    for (int m = 0; m < 4; ++m) {
        f32x4 acc = (f32x4){0.f, 0.f, 0.f, 0.f};
#pragma unroll
        for (int kt = 0; kt < 4; ++kt) {
            long ar = (row0 + m * 16 + l15) * NH + kt * 32 + 8 * lg;
            short8v ah = *(const short8v*)(Ahi + ar);
            short8v al = *(const short8v*)(Alo + ar);
            acc = __builtin_amdgcn_mfma_f32_16x16x32_bf16(ah, Bh[kt], acc, 0, 0, 0);
            acc = __builtin_amdgcn_mfma_f32_16x16x32_bf16(al, Bh[kt], acc, 0, 0, 0);
        }
#pragma unroll
        for (int r = 0; r < 4; ++r)
            out[(row0 + m * 16 + 4 * lg + r) * NH + j0 + l15] = acc[r];
    }
}

// ---------------- degree accumulation ---------------------------------------
__global__ void degacc_k(const int* __restrict__ ei, const float* __restrict__ ew,
                         float* deg, int* cnt) {
    int e = blockIdx.x * 256 + threadIdx.x;
    if (e < NE) {
        int d = ei[NE + e];
        atomicAdd(&deg[d], ew[e]);
        atomicAdd(&cnt[d], 1);
    }
}

// ---------------- scan (+ dinv) ---------------------------------------------
__global__ __launch_bounds__(1024) void scan_k(const int* __restrict__ cnt,
                                               int* __restrict__ rowp,
                                               const float* __restrict__ deg,
                                               float* __restrict__ dinv) {
    for (int idx = threadIdx.x; idx < NN; idx += 1024) {
        float d = deg[idx];
        dinv[idx] = d > 0.f ? rsqrtf(d) : 0.f;
    }
    __shared__ int sA[1024];
    __shared__ int sB[1024];
    const int tid = threadIdx.x;
    const int CH = 10;
    int base = tid * CH;
    int local[CH];
    int ssum = 0;
#pragma unroll
    for (int i = 0; i < CH; ++i) {
        int idx = base + i;
        int v = (idx < NN) ? cnt[idx] : 0;
        local[i] = v; ssum += v;
    }
    int* src = sA; int* dst = sB;
    src[tid] = ssum;
    __syncthreads();
    for (int off = 1; off < 1024; off <<= 1) {
        int v = src[tid];
        if (tid >= off) v += src[tid - off];
        dst[tid] = v;
        __syncthreads();
        int* tmp = src; src = dst; dst = tmp;
    }
    int run = src[tid] - ssum;
#pragma unroll
    for (int i = 0; i < CH; ++i) {
        int idx = base + i;
        if (idx < NN) rowp[idx] = run;
        run += local[i];
    }
    if (tid == 1023) rowp[NN] = src[1023];
}

__global__ void scatter_k(const int* __restrict__ ei, const float* __restrict__ ew,
                          const float* __restrict__ dinv, const int* __restrict__ rowp,
                          int* fill, int* __restrict__ col, float* __restrict__ val)
{
    int e = blockIdx.x * 256 + threadIdx.x;
    if (e >= NE) return;
    int srcn = ei[e], d = ei[NE + e];
    int pos = rowp[d] + atomicAdd(&fill[d], 1);
    col[pos] = srcn;
    val[pos] = dinv[srcn] * ew[e] * dinv[d];
}

// ---------- gather v4: NODE-MAJOR xl[n][b][128] — 4KB coalesced per edge ----
template<int EMIT>
__global__ __launch_bounds__(256) void gather4_k(const float* __restrict__ xl,
    const int* __restrict__ rowp, const int* __restrict__ col,
    const float* __restrict__ val, const float* __restrict__ dinv,
    const float* __restrict__ bias,
    u16* __restrict__ ohi, u16* __restrict__ olo,
    const float* __restrict__ fcw, const float* __restrict__ fcb,
    float* __restrict__ out)
{
    __shared__ float hrow[8][132];
    __shared__ float wl[16][132];
    const int n = blockIdx.x;
    const int tid = threadIdx.x;
    const int q = tid & 31;            // channel-quad (bias index)
    if (EMIT == 1) {
        for (int l = tid; l < 16 * 128; l += 256)
            wl[l >> 7][l & 127] = fcw[l];
    }
    const float dn = dinv[n];
    const float sn = dn * dn;          // self-loop norm
    float4 acc = *(const float4*)(xl + (long)n * 1024 + tid * 4);
    acc.x *= sn; acc.y *= sn; acc.z *= sn; acc.w *= sn;
    int e = rowp[n];
    const int e1 = rowp[n + 1];
    for (; e + 2 <= e1; e += 2) {      // edge scalars wave-uniform -> s_load
        const int s0 = col[e], s1 = col[e + 1];
        const float w0 = val[e], w1 = val[e + 1];
        const float4 u0 = *(const float4*)(xl + (long)s0 * 1024 + tid * 4);
        const float4 u1 = *(const float4*)(xl + (long)s1 * 1024 + tid * 4);
        acc.x = fmaf(w0, u0.x, acc.x); acc.y = fmaf(w0, u0.y, acc.y);
        acc.z = fmaf(w0, u0.z, acc.z); acc.w = fmaf(w0, u0.w, acc.w);
        acc.x = fmaf(w1, u1.x, acc.x); acc.y = fmaf(w1, u1.y, acc.y);
        acc.z = fmaf(w1, u1.z, acc.z); acc.w = fmaf(w1, u1.w, acc.w);
    }
    if (e < e1) {
        const int s0 = col[e];
        const float w0 = val[e];
        const float4 u0 = *(const float4*)(xl + (long)s0 * 1024 + tid * 4);
        acc.x = fmaf(w0, u0.x, acc.x); acc.y = fmaf(w0, u0.y, acc.y);
        acc.z = fmaf(w0, u0.z, acc.z); acc.w = fmaf(w0, u0.w, acc.w);
    }
    const float4 bb = ((const float4*)bias)[q];
    const float o0 = fmaxf(acc.x + bb.x, 0.f);
    const float o1 = fmaxf(acc.y + bb.y, 0.f);
    const float o2 = fmaxf(acc.z + bb.z, 0.f);
    const float o3 = fmaxf(acc.w + bb.w, 0.f);
    if (EMIT == 0) {
        unsigned int p0 = pack_split(o0), p1 = pack_split(o1);
        unsigned int p2 = pack_split(o2), p3 = pack_split(o3);
        ushort4 hi4 = make_ushort4((u16)p0, (u16)p1, (u16)p2, (u16)p3);
        ushort4 lo4 = make_ushort4((u16)(p0 >> 16), (u16)(p1 >> 16),
                                   (u16)(p2 >> 16), (u16)(p3 >> 16));
        *(ushort4*)(ohi + (long)n * 1024 + tid * 4) = hi4;
        *(ushort4*)(olo + (long)n * 1024 + tid * 4) = lo4;
    } else {
        const int b = tid >> 5;
        *(float4*)&hrow[b][q * 4] = make_float4(o0, o1, o2, o3);
        __syncthreads();
        if (tid < 128) {
            const int b2 = tid >> 4, o = tid & 15;
            float a = fcb[o];
#pragma unroll 8
            for (int k = 0; k < NH; ++k) a = fmaf(hrow[b2][k], wl[o][k], a);
            out[((long)b2 * NN + n) * 16 + o] = a;
        }
    }
}

// ---------------------------------------------------------------------------
extern "C" void kernel_launch(void* const* d_in, const int* in_sizes, int n_in,
                              void* d_out, int out_size, void* d_ws, size_t ws_size,
                              hipStream_t stream)
{
    const float* x   = (const float*)d_in[0];
    const int*   ei  = (const int*)d_in[1];
    const float* ew  = (const float*)d_in[2];
    const float* Wih = (const float*)d_in[3];
    const float* Whh = (const float*)d_in[4];
    const float* bih = (const float*)d_in[5];
    const float* bhh = (const float*)d_in[6];
    const float* g1w = (const float*)d_in[7];
    const float* g1b = (const float*)d_in[8];
    const float* g2w = (const float*)d_in[9];
    const float* g2b = (const float*)d_in[10];
    const float* fcw = (const float*)d_in[11];
    const float* fcb = (const float*)d_in[12];
    float* out = (float*)d_out;

    char* ws = (char*)d_ws;
    u16* whh_hi  = (u16*)(ws + 0);           // 131072
    u16* wih_hi2 = (u16*)(ws + 131072);      // 32768
    u16* wih_lo2 = (u16*)(ws + 163840);      // 32768
    u16* g1hi    = (u16*)(ws + 196608);      // 32768
    u16* g2hi    = (u16*)(ws + 229376);      // 32768
    float* deg   = (float*)(ws + 262144);
    float* dinv  = (float*)(ws + 303104);
    int*   cnt   = (int*)(ws + 344064);
    int*   fill  = (int*)(ws + 385024);
    int*   rowp  = (int*)(ws + 425984);
    int*   col   = (int*)(ws + 466176);      // 640000
    float* val   = (float*)(ws + 1106176);   // 640000
    u16* hhi     = (u16*)(ws + 2097152);     // 20480000 (node-major)
    u16* hlo     = (u16*)(ws + 22577152);    // 20480000 (node-major)
    float* xl    = (float*)(ws + 43057152);  // 40960000 (node-major)

    prep_w_k<<<256, 256, 0, stream>>>(Whh, Wih, g1w, g2w, whh_hi,
                                      wih_hi2, wih_lo2, g1hi, g2hi,
                                      deg, cnt, fill);
    lstm4b_k<<<BN / 64, 512, 0, stream>>>(x, whh_hi, wih_hi2, wih_lo2,
                                          bih, bhh, hhi, hlo);

    degacc_k<<<(NE + 255) / 256, 256, 0, stream>>>(ei, ew, deg, cnt);
    scan_k<<<1, 1024, 0, stream>>>(cnt, rowp, deg, dinv);
    scatter_k<<<(NE + 255) / 256, 256, 0, stream>>>(ei, ew, dinv, rowp, fill, col, val);

    gemmx2_k<<<BN / 64, 512, 0, stream>>>(hhi, hlo, g1hi, xl);
    gather4_k<0><<<NN, 256, 0, stream>>>(xl, rowp, col, val, dinv, g1b,
                                         hhi, hlo, nullptr, nullptr, nullptr);
    gemmx2_k<<<BN / 64, 512, 0, stream>>>(hhi, hlo, g2hi, xl);
    gather4_k<1><<<NN, 256, 0, stream>>>(xl, rowp, col, val, dinv, g2b,
                                         nullptr, nullptr, fcw, fcb, out);
}

// Round 11
// 525.283 us; speedup vs baseline: 1.2862x; 1.2862x over previous
//
#include <hip/hip_runtime.h>
#include <math.h>

#define NB 8
#define NN 10000
#define NT 12
#define ND 16
#define NH 128
#define NE 160000
#define BN (NB * NN)  // 80000

typedef __attribute__((ext_vector_type(8))) short short8v;
typedef __attribute__((ext_vector_type(4))) float f32x4;
typedef unsigned short u16;

#define NL2E  -1.442695041f   // -log2(e)
#define N2L2E -2.885390082f   // -2*log2(e)

__device__ __forceinline__ u16 bf16_rn(float f) {
    unsigned int u = __float_as_uint(f);
    u += 0x7fffu + ((u >> 16) & 1u);
    return (u16)(u >> 16);
}
__device__ __forceinline__ float bf16f(u16 s) {
    return __uint_as_float((unsigned int)s << 16);
}
// trunc-hi + rn-lo split packed as (lo<<16)|hi
__device__ __forceinline__ unsigned int pack_split(float f) {
    unsigned int u = __float_as_uint(f);
    unsigned int hh = u >> 16;
    float rem = f - __uint_as_float(u & 0xffff0000u);
    unsigned int hl = bf16_rn(rem);
    return (hl << 16) | hh;
}

// ---------- prep: scaled bf16 weights (exp2 gates) + CSR init ---------------
__global__ void prep_w_k(const float* __restrict__ Whh, const float* __restrict__ Wih,
                         const float* __restrict__ g1w, const float* __restrict__ g2w,
                         u16* __restrict__ whh_hi, u16* __restrict__ wih_hi2,
                         u16* __restrict__ g1hi, u16* __restrict__ g2hi,
                         float* __restrict__ deg, int* __restrict__ cnt, int* __restrict__ fill)
{
    int i = blockIdx.x * 256 + threadIdx.x;   // 65536 threads
    if (i < 512 * 128) {
        int j = i >> 7;
        float s = ((j >> 7) == 2) ? N2L2E : NL2E;
        whh_hi[i] = bf16_rn(s * Whh[i]);
    }
    if (i < 512 * 16) {
        int row = i >> 4, d = i & 15;
        float s = ((row >> 7) == 2) ? N2L2E : NL2E;
        u16 h = bf16_rn(s * Wih[i]);
        wih_hi2[row * 32 + d] = h;        // duplicated: pairs with [x_hi; x_lo]
        wih_hi2[row * 32 + 16 + d] = h;
    }
    if (i < 128 * 128) {
        g1hi[i] = bf16_rn(g1w[i]);
        g2hi[i] = bf16_rn(g2w[i]);
    }
    if (i < NN) { deg[i] = 1.0f; cnt[i] = 0; fill[i] = 0; }   // 1.0 = self-loop
}

// ---------- LSTM v4c: single-plane (bf16-rn) recurrence, exp2 epilogue ------
// Round-9 lstm4 structure, (512,2) spill-free, but: h recurrence keeps ONLY
// the bf16-hi plane (20 MFMA/m-tile instead of 40); final h emitted hi+lo.
__global__ __launch_bounds__(512, 2) void lstm4c_k(
    const float* __restrict__ x,
    const u16* __restrict__ whh_hi, const u16* __restrict__ wih_hi2,
    const float* __restrict__ bih, const float* __restrict__ bhh,
    u16* __restrict__ hhi_g, u16* __restrict__ hlo_g)
{
    __shared__ __align__(16) u16 Hhi[2][64][128];   // 32 KB (double-buffered)
    __shared__ __align__(16) u16 HloF[64][128];     // 16 KB (final step only)
    __shared__ __align__(16) u16 Hx[2][64][40];     // 10 KB (80B rows)
    const int tid = threadIdx.x;
    const int lane = tid & 63;
    const int wid = tid >> 6;
    const int j0 = wid * 16;
    const int l15 = lane & 15;
    const int lg = lane >> 4;          // 0..3
    const long seq0 = (long)blockIdx.x * 64;
    const int swzr = (l15 & 7) << 3;   // read-side XOR swizzle
    const int xs_seq = tid >> 3;       // x staging: 8 threads/seq-row
    const int xd0 = (tid & 7) * 2;

    // B fragments in registers: Whh (scaled bf16, 64 VGPR) + Wih (16 VGPR)
    short8v Bh[4][4];                  // [kt][gate]
    short8v b1[4];
    float bv[4];
#pragma unroll
    for (int kt = 0; kt < 4; ++kt)
#pragma unroll
        for (int g = 0; g < 4; ++g) {
            int row = g * NH + j0 + l15;
            Bh[kt][g] = *(const short8v*)(whh_hi + row * NH + kt * 32 + 8 * lg);
        }
#pragma unroll
    for (int g = 0; g < 4; ++g) {
        int row = g * NH + j0 + l15;
        b1[g] = *(const short8v*)(wih_hi2 + row * 32 + 8 * lg);
        bv[g] = (bih[row] + bhh[row]) * ((g == 2) ? N2L2E : NL2E);
    }

    // stage x for t=0 ([x_hi ; x_lo] halves)
    {
        float2 xv = *(const float2*)(x + ((seq0 + xs_seq) * NT + 0) * ND + xd0);
        unsigned int p0 = pack_split(xv.x), p1 = pack_split(xv.y);
        *(ushort2*)&Hx[0][xs_seq][xd0] = make_ushort2((u16)p0, (u16)p1);
        *(ushort2*)&Hx[0][xs_seq][16 + xd0] = make_ushort2((u16)(p0 >> 16), (u16)(p1 >> 16));
    }
    f32x4 c[4];
#pragma unroll
    for (int m = 0; m < 4; ++m) c[m] = (f32x4){0.f, 0.f, 0.f, 0.f};
    __syncthreads();

    for (int t = 0; t < NT; ++t) {
        const int cur = t & 1, nxt = cur ^ 1;
        const bool last = (t == NT - 1);
        float2 xv;
        if (t + 1 < NT)
            xv = *(const float2*)(x + ((seq0 + xs_seq) * NT + (t + 1)) * ND + xd0);

#pragma unroll
        for (int m = 0; m < 4; ++m) {
            const int sq = m * 16 + l15;
            short8v xa = *(const short8v*)&Hx[cur][sq][8 * lg];

            f32x4 acc[4];
#pragma unroll
            for (int g = 0; g < 4; ++g)
                acc[g] = (f32x4){bv[g], bv[g], bv[g], bv[g]};

            if (t > 0) {
#pragma unroll
                for (int kt = 0; kt < 4; ++kt) {
                    const int kk = (kt * 32 + 8 * lg) ^ swzr;
                    short8v ah = *(const short8v*)&Hhi[cur][sq][kk];
#pragma unroll
                    for (int g = 0; g < 4; ++g)
                        acc[g] = __builtin_amdgcn_mfma_f32_16x16x32_bf16(ah, Bh[kt][g], acc[g], 0, 0, 0);
                }
            }
#pragma unroll
            for (int g = 0; g < 4; ++g)
                acc[g] = __builtin_amdgcn_mfma_f32_16x16x32_bf16(xa, b1[g], acc[g], 0, 0, 0);

            // epilogue: 5 exp2 + 3 paired rcp per element (pre-scaled gates)
#pragma unroll
            for (int r = 0; r < 4; ++r) {
                const float ui = exp2f(acc[0][r]);
                const float uf = exp2f(acc[1][r]);
                const float ug = exp2f(acc[2][r]);
                const float uo = exp2f(acc[3][r]);
                const float di = 1.f + ui, df = 1.f + uf;
                const float dg = 1.f + ug, dd = 1.f + uo;
                const float r0 = __builtin_amdgcn_rcpf(di * df);
                const float r1 = __builtin_amdgcn_rcpf(dg * dd);
                const float si = r0 * df;                   // sigmoid(i)
                const float sf = r0 * di;                   // sigmoid(f)
                const float tg = fmaf(2.f, r1 * dd, -1.f);  // tanh(g)
                const float so = r1 * dg;                   // sigmoid(o)
                const float cc = fmaf(sf, c[m][r], si * tg);
                c[m][r] = cc;
                const float uc = exp2f(cc * N2L2E);
                const float rc = __builtin_amdgcn_rcpf(1.f + uc);
                const float hv = fmaf(2.f, so * rc, -so);   // o * tanh(c)
                const int sq2 = m * 16 + 4 * lg + r;
                const int jj = (j0 + l15) ^ ((sq2 & 7) << 3);
                if (!last) {
                    Hhi[nxt][sq2][jj] = bf16_rn(hv);        // rn for recurrence
                } else {
                    unsigned int p = pack_split(hv);        // hi+lo for GCN
                    Hhi[nxt][sq2][jj] = (u16)p;
                    HloF[sq2][jj] = (u16)(p >> 16);
                }
            }
        }

        if (t + 1 < NT) {
            unsigned int p0 = pack_split(xv.x), p1 = pack_split(xv.y);
            *(ushort2*)&Hx[nxt][xs_seq][xd0] = make_ushort2((u16)p0, (u16)p1);
            *(ushort2*)&Hx[nxt][xs_seq][16 + xd0] = make_ushort2((u16)(p0 >> 16), (u16)(p1 >> 16));
        }
        __syncthreads();
    }

    // copy-out (node-major rows n*8+b): final h in Hhi[0] / HloF
    for (int ci = tid; ci < 2048; ci += 512) {
        int plane = ci >> 10;
        int rem = ci & 1023;
        int s = rem >> 4, g16 = rem & 15;
        int sg = g16 ^ (s & 7);
        unsigned int sglob = (unsigned int)(seq0 + s);
        unsigned int b = sglob / NN;
        unsigned int n = sglob - b * NN;
        const uint4* src = (const uint4*)(plane ? &HloF[s][sg * 8] : &Hhi[0][s][sg * 8]);
        uint4* dst = (uint4*)((plane ? hlo_g : hhi_g) + ((long)n * 8 + b) * NH + g16 * 8);
        *dst = *src;
    }
}

// ---------- GCN GEMM: out = A @ W^T, A hi/lo planes, OUTPUT bf16 ------------
__global__ __launch_bounds__(512) void gemmx3_k(
    const u16* __restrict__ Ahi, const u16* __restrict__ Alo,
    const u16* __restrict__ Whi, u16* __restrict__ out)
{
    const int tid = threadIdx.x;
    const int lane = tid & 63;
    const int wid = tid >> 6;
    const int j0 = wid * 16;
    const int l15 = lane & 15;
    const int lg = lane >> 4;
    const long row0 = (long)blockIdx.x * 64;

    short8v Bh[4];
#pragma unroll
    for (int kt = 0; kt < 4; ++kt)
        Bh[kt] = *(const short8v*)(Whi + (j0 + l15) * NH + kt * 32 + 8 * lg);

#pragma unroll
    for (int m = 0; m < 4; ++m) {
        f32x4 acc = (f32x4){0.f, 0.f, 0.f, 0.f};
#pragma unroll
        for (int kt = 0; kt < 4; ++kt) {
            long ar = (row0 + m * 16 + l15) * NH + kt * 32 + 8 * lg;
            short8v ah = *(const short8v*)(Ahi + ar);
            short8v al = *(const short8v*)(Alo + ar);
            acc = __builtin_amdgcn_mfma_f32_16x16x32_bf16(ah, Bh[kt], acc, 0, 0, 0);
            acc = __builtin_amdgcn_mfma_f32_16x16x32_bf16(al, Bh[kt], acc, 0, 0, 0);
        }
#pragma unroll
        for (int r = 0; r < 4; ++r)
            out[(row0 + m * 16 + 4 * lg + r) * NH + j0 + l15] = bf16_rn(acc[r]);
    }
}

// ---------------- degree accumulation ---------------------------------------
__global__ void degacc_k(const int* __restrict__ ei, const float* __restrict__ ew,
                         float* deg, int* cnt) {
    int e = blockIdx.x * 256 + threadIdx.x;
    if (e < NE) {
        int d = ei[NE + e];
        atomicAdd(&deg[d], ew[e]);
        atomicAdd(&cnt[d], 1);
    }
}

// ---------------- scan (+ dinv) ---------------------------------------------
__global__ __launch_bounds__(1024) void scan_k(const int* __restrict__ cnt,
                                               int* __restrict__ rowp,
                                               const float* __restrict__ deg,
                                               float* __restrict__ dinv) {
    for (int idx = threadIdx.x; idx < NN; idx += 1024) {
        float d = deg[idx];
        dinv[idx] = d > 0.f ? rsqrtf(d) : 0.f;
    }
    __shared__ int sA[1024];
    __shared__ int sB[1024];
    const int tid = threadIdx.x;
    const int CH = 10;
    int base = tid * CH;
    int local[CH];
    int ssum = 0;
#pragma unroll
    for (int i = 0; i < CH; ++i) {
        int idx = base + i;
        int v = (idx < NN) ? cnt[idx] : 0;
        local[i] = v; ssum += v;
    }
    int* src = sA; int* dst = sB;
    src[tid] = ssum;
    __syncthreads();
    for (int off = 1; off < 1024; off <<= 1) {
        int v = src[tid];
        if (tid >= off) v += src[tid - off];
        dst[tid] = v;
        __syncthreads();
        int* tmp = src; src = dst; dst = tmp;
    }
    int run = src[tid] - ssum;
#pragma unroll
    for (int i = 0; i < CH; ++i) {
        int idx = base + i;
        if (idx < NN) rowp[idx] = run;
        run += local[i];
    }
    if (tid == 1023) rowp[NN] = src[1023];
}

__global__ void scatter_k(const int* __restrict__ ei, const float* __restrict__ ew,
                          const float* __restrict__ dinv, const int* __restrict__ rowp,
                          int* fill, int* __restrict__ col, float* __restrict__ val)
{
    int e = blockIdx.x * 256 + threadIdx.x;
    if (e >= NE) return;
    int srcn = ei[e], d = ei[NE + e];
    int pos = rowp[d] + atomicAdd(&fill[d], 1);
    col[pos] = srcn;
    val[pos] = dinv[srcn] * ew[e] * dinv[d];
}

// ---------- gather v5: node-major bf16 xl[n][b*128] — 2KB row per edge ------
template<int EMIT>
__global__ __launch_bounds__(256) void gather5_k(const u16* __restrict__ xlb,
    const int* __restrict__ rowp, const int* __restrict__ col,
    const float* __restrict__ val, const float* __restrict__ dinv,
    const float* __restrict__ bias,
    u16* __restrict__ ohi, u16* __restrict__ olo,
    const float* __restrict__ fcw, const float* __restrict__ fcb,
    float* __restrict__ out)
{
    __shared__ float hrow[8][132];
    __shared__ float wl[16][132];
    const int n = blockIdx.x;
    const int tid = threadIdx.x;
    const int q = tid & 31;            // channel-quad (bias index)
    if (EMIT == 1) {
        for (int l = tid; l < 16 * 128; l += 256)
            wl[l >> 7][l & 127] = fcw[l];
    }
    const float dn = dinv[n];
    const float sn = dn * dn;          // self-loop norm
    float4 acc;
    {
        ushort4 u = *(const ushort4*)(xlb + (long)n * 1024 + tid * 4);
        acc.x = sn * bf16f(u.x); acc.y = sn * bf16f(u.y);
        acc.z = sn * bf16f(u.z); acc.w = sn * bf16f(u.w);
    }
    int e = rowp[n];
    const int e1 = rowp[n + 1];
    for (; e + 2 <= e1; e += 2) {      // edge scalars wave-uniform -> s_load
        const int s0 = col[e], s1 = col[e + 1];
        const float w0 = val[e], w1 = val[e + 1];
        const ushort4 u0 = *(const ushort4*)(xlb + (long)s0 * 1024 + tid * 4);
        const ushort4 u1 = *(const ushort4*)(xlb + (long)s1 * 1024 + tid * 4);
        acc.x = fmaf(w0, bf16f(u0.x), acc.x); acc.y = fmaf(w0, bf16f(u0.y), acc.y);
        acc.z = fmaf(w0, bf16f(u0.z), acc.z); acc.w = fmaf(w0, bf16f(u0.w), acc.w);
        acc.x = fmaf(w1, bf16f(u1.x), acc.x); acc.y = fmaf(w1, bf16f(u1.y), acc.y);
        acc.z = fmaf(w1, bf16f(u1.z), acc.z); acc.w = fmaf(w1, bf16f(u1.w), acc.w);
    }
    if (e < e1) {
        const int s0 = col[e];
        const float w0 = val[e];
        const ushort4 u0 = *(const ushort4*)(xlb + (long)s0 * 1024 + tid * 4);
        acc.x = fmaf(w0, bf16f(u0.x), acc.x); acc.y = fmaf(w0, bf16f(u0.y), acc.y);
        acc.z = fmaf(w0, bf16f(u0.z), acc.z); acc.w = fmaf(w0, bf16f(u0.w), acc.w);
    }
    const float4 bb = ((const float4*)bias)[q];
    const float o0 = fmaxf(acc.x + bb.x, 0.f);
    const float o1 = fmaxf(acc.y + bb.y, 0.f);
    const float o2 = fmaxf(acc.z + bb.z, 0.f);
    const float o3 = fmaxf(acc.w + bb.w, 0.f);
    if (EMIT == 0) {
        unsigned int p0 = pack_split(o0), p1 = pack_split(o1);
        unsigned int p2 = pack_split(o2), p3 = pack_split(o3);
        ushort4 hi4 = make_ushort4((u16)p0, (u16)p1, (u16)p2, (u16)p3);
        ushort4 lo4 = make_ushort4((u16)(p0 >> 16), (u16)(p1 >> 16),
                                   (u16)(p2 >> 16), (u16)(p3 >> 16));
        *(ushort4*)(ohi + (long)n * 1024 + tid * 4) = hi4;
        *(ushort4*)(olo + (long)n * 1024 + tid * 4) = lo4;
    } else {
        const int b = tid >> 5;
        *(float4*)&hrow[b][q * 4] = make_float4(o0, o1, o2, o3);
        __syncthreads();
        if (tid < 128) {
            const int b2 = tid >> 4, o = tid & 15;
            float a = fcb[o];
#pragma unroll 8
            for (int k = 0; k < NH; ++k) a = fmaf(hrow[b2][k], wl[o][k], a);
            out[((long)b2 * NN + n) * 16 + o] = a;
        }
    }
}

// ---------------------------------------------------------------------------
extern "C" void kernel_launch(void* const* d_in, const int* in_sizes, int n_in,
                              void* d_out, int out_size, void* d_ws, size_t ws_size,
                              hipStream_t stream)
{
    const float* x   = (const float*)d_in[0];
    const int*   ei  = (const int*)d_in[1];
    const float* ew  = (const float*)d_in[2];
    const float* Wih = (const float*)d_in[3];
    const float* Whh = (const float*)d_in[4];
    const float* bih = (const float*)d_in[5];
    const float* bhh = (const float*)d_in[6];
    const float* g1w = (const float*)d_in[7];
    const float* g1b = (const float*)d_in[8];
    const float* g2w = (const float*)d_in[9];
    const float* g2b = (const float*)d_in[10];
    const float* fcw = (const float*)d_in[11];
    const float* fcb = (const float*)d_in[12];
    float* out = (float*)d_out;

    char* ws = (char*)d_ws;
    u16* whh_hi  = (u16*)(ws + 0);           // 131072
    u16* wih_hi2 = (u16*)(ws + 131072);      // 32768
    u16* g1hi    = (u16*)(ws + 196608);      // 32768
    u16* g2hi    = (u16*)(ws + 229376);      // 32768
    float* deg   = (float*)(ws + 262144);
    float* dinv  = (float*)(ws + 303104);
    int*   cnt   = (int*)(ws + 344064);
    int*   fill  = (int*)(ws + 385024);
    int*   rowp  = (int*)(ws + 425984);
    int*   col   = (int*)(ws + 466176);      // 640000
    float* val   = (float*)(ws + 1106176);   // 640000
    u16* hhi     = (u16*)(ws + 2097152);     // 20480000 (node-major)
    u16* hlo     = (u16*)(ws + 22577152);    // 20480000 (node-major)
    u16* xlb     = (u16*)(ws + 43057152);    // 20480000 (node-major bf16)

    prep_w_k<<<256, 256, 0, stream>>>(Whh, Wih, g1w, g2w, whh_hi, wih_hi2,
                                      g1hi, g2hi, deg, cnt, fill);
    lstm4c_k<<<BN / 64, 512, 0, stream>>>(x, whh_hi, wih_hi2, bih, bhh, hhi, hlo);

    degacc_k<<<(NE + 255) / 256, 256, 0, stream>>>(ei, ew, deg, cnt);
    scan_k<<<1, 1024, 0, stream>>>(cnt, rowp, deg, dinv);
    scatter_k<<<(NE + 255) / 256, 256, 0, stream>>>(ei, ew, dinv, rowp, fill, col, val);

    gemmx3_k<<<BN / 64, 512, 0, stream>>>(hhi, hlo, g1hi, xlb);
    gather5_k<0><<<NN, 256, 0, stream>>>(xlb, rowp, col, val, dinv, g1b,
                                         hhi, hlo, nullptr, nullptr, nullptr);
    gemmx3_k<<<BN / 64, 512, 0, stream>>>(hhi, hlo, g2hi, xlb);
    gather5_k<1><<<NN, 256, 0, stream>>>(xlb, rowp, col, val, dinv, g2b,
                                         nullptr, nullptr, fcw, fcb, out);
}

// Round 12
// 477.323 us; speedup vs baseline: 1.4155x; 1.1005x over previous
//
#include <hip/hip_runtime.h>
#include <math.h>

#define NB 8
#define NN 10000
#define NT 12
#define ND 16
#define NH 128
#define NE 160000
#define BN (NB * NN)  // 80000

typedef __attribute__((ext_vector_type(8))) short short8v;
typedef __attribute__((ext_vector_type(4))) float f32x4;
typedef unsigned short u16;

#define NL2E  -1.442695041f   // -log2(e)
#define N2L2E -2.885390082f   // -2*log2(e)

__device__ __forceinline__ u16 bf16_rn(float f) {
    unsigned int u = __float_as_uint(f);
    u += 0x7fffu + ((u >> 16) & 1u);
    return (u16)(u >> 16);
}
__device__ __forceinline__ float bf16f(u16 s) {
    return __uint_as_float((unsigned int)s << 16);
}
// trunc-hi + rn-lo split packed as (lo<<16)|hi  (x staging keeps hi/lo)
__device__ __forceinline__ unsigned int pack_split(float f) {
    unsigned int u = __float_as_uint(f);
    unsigned int hh = u >> 16;
    float rem = f - __uint_as_float(u & 0xffff0000u);
    unsigned int hl = bf16_rn(rem);
    return (hl << 16) | hh;
}

// ---------- prep: scaled bf16 weights (exp2 gates) + CSR init ---------------
__global__ void prep_w_k(const float* __restrict__ Whh, const float* __restrict__ Wih,
                         const float* __restrict__ g1w, const float* __restrict__ g2w,
                         u16* __restrict__ whh_hi, u16* __restrict__ wih_hi2,
                         u16* __restrict__ g1hi, u16* __restrict__ g2hi,
                         float* __restrict__ deg, int* __restrict__ cnt, int* __restrict__ fill)
{
    int i = blockIdx.x * 256 + threadIdx.x;   // 65536 threads
    if (i < 512 * 128) {
        int j = i >> 7;
        float s = ((j >> 7) == 2) ? N2L2E : NL2E;
        whh_hi[i] = bf16_rn(s * Whh[i]);
    }
    if (i < 512 * 16) {
        int row = i >> 4, d = i & 15;
        float s = ((row >> 7) == 2) ? N2L2E : NL2E;
        u16 h = bf16_rn(s * Wih[i]);
        wih_hi2[row * 32 + d] = h;        // duplicated: pairs with [x_hi; x_lo]
        wih_hi2[row * 32 + 16 + d] = h;
    }
    if (i < 128 * 128) {
        g1hi[i] = bf16_rn(g1w[i]);
        g2hi[i] = bf16_rn(g2w[i]);
    }
    if (i < NN) { deg[i] = 1.0f; cnt[i] = 0; fill[i] = 0; }   // 1.0 = self-loop
}

// ---------- LSTM v4d: single-plane recurrence AND output, exp2 epilogue -----
// (512,2) spill-free; h kept/emitted as plain bf16-rn everywhere.
__global__ __launch_bounds__(512, 2) void lstm4d_k(
    const float* __restrict__ x,
    const u16* __restrict__ whh_hi, const u16* __restrict__ wih_hi2,
    const float* __restrict__ bih, const float* __restrict__ bhh,
    u16* __restrict__ hhi_g)
{
    __shared__ __align__(16) u16 Hhi[2][64][128];   // 32 KB (double-buffered)
    __shared__ __align__(16) u16 Hx[2][64][40];     // 10 KB (80B rows)
    const int tid = threadIdx.x;
    const int lane = tid & 63;
    const int wid = tid >> 6;
    const int j0 = wid * 16;
    const int l15 = lane & 15;
    const int lg = lane >> 4;          // 0..3
    const long seq0 = (long)blockIdx.x * 64;
    const int swzr = (l15 & 7) << 3;   // read-side XOR swizzle
    const int xs_seq = tid >> 3;       // x staging: 8 threads/seq-row
    const int xd0 = (tid & 7) * 2;

    // B fragments in registers: Whh (scaled bf16, 64 VGPR) + Wih (16 VGPR)
    short8v Bh[4][4];                  // [kt][gate]
    short8v b1[4];
    float bv[4];
#pragma unroll
    for (int kt = 0; kt < 4; ++kt)
#pragma unroll
        for (int g = 0; g < 4; ++g) {
            int row = g * NH + j0 + l15;
            Bh[kt][g] = *(const short8v*)(whh_hi + row * NH + kt * 32 + 8 * lg);
        }
#pragma unroll
    for (int g = 0; g < 4; ++g) {
        int row = g * NH + j0 + l15;
        b1[g] = *(const short8v*)(wih_hi2 + row * 32 + 8 * lg);
        bv[g] = (bih[row] + bhh[row]) * ((g == 2) ? N2L2E : NL2E);
    }

    // stage x for t=0 ([x_hi ; x_lo] halves)
    {
        float2 xv = *(const float2*)(x + ((seq0 + xs_seq) * NT + 0) * ND + xd0);
        unsigned int p0 = pack_split(xv.x), p1 = pack_split(xv.y);
        *(ushort2*)&Hx[0][xs_seq][xd0] = make_ushort2((u16)p0, (u16)p1);
        *(ushort2*)&Hx[0][xs_seq][16 + xd0] = make_ushort2((u16)(p0 >> 16), (u16)(p1 >> 16));
    }
    f32x4 c[4];
#pragma unroll
    for (int m = 0; m < 4; ++m) c[m] = (f32x4){0.f, 0.f, 0.f, 0.f};
    __syncthreads();

    for (int t = 0; t < NT; ++t) {
        const int cur = t & 1, nxt = cur ^ 1;
        float2 xv;
        if (t + 1 < NT)
            xv = *(const float2*)(x + ((seq0 + xs_seq) * NT + (t + 1)) * ND + xd0);

#pragma unroll
        for (int m = 0; m < 4; ++m) {
            const int sq = m * 16 + l15;
            short8v xa = *(const short8v*)&Hx[cur][sq][8 * lg];

            f32x4 acc[4];
#pragma unroll
            for (int g = 0; g < 4; ++g)
                acc[g] = (f32x4){bv[g], bv[g], bv[g], bv[g]};

            if (t > 0) {
#pragma unroll
                for (int kt = 0; kt < 4; ++kt) {
                    const int kk = (kt * 32 + 8 * lg) ^ swzr;
                    short8v ah = *(const short8v*)&Hhi[cur][sq][kk];
#pragma unroll
                    for (int g = 0; g < 4; ++g)
                        acc[g] = __builtin_amdgcn_mfma_f32_16x16x32_bf16(ah, Bh[kt][g], acc[g], 0, 0, 0);
                }
            }
#pragma unroll
            for (int g = 0; g < 4; ++g)
                acc[g] = __builtin_amdgcn_mfma_f32_16x16x32_bf16(xa, b1[g], acc[g], 0, 0, 0);

            // epilogue: 5 exp2 + 3 paired rcp per element (pre-scaled gates)
#pragma unroll
            for (int r = 0; r < 4; ++r) {
                const float ui = exp2f(acc[0][r]);
                const float uf = exp2f(acc[1][r]);
                const float ug = exp2f(acc[2][r]);
                const float uo = exp2f(acc[3][r]);
                const float di = 1.f + ui, df = 1.f + uf;
                const float dg = 1.f + ug, dd = 1.f + uo;
                const float r0 = __builtin_amdgcn_rcpf(di * df);
                const float r1 = __builtin_amdgcn_rcpf(dg * dd);
                const float si = r0 * df;                   // sigmoid(i)
                const float sf = r0 * di;                   // sigmoid(f)
                const float tg = fmaf(2.f, r1 * dd, -1.f);  // tanh(g)
                const float so = r1 * dg;                   // sigmoid(o)
                const float cc = fmaf(sf, c[m][r], si * tg);
                c[m][r] = cc;
                const float uc = exp2f(cc * N2L2E);
                const float rc = __builtin_amdgcn_rcpf(1.f + uc);
                const float hv = fmaf(2.f, so * rc, -so);   // o * tanh(c)
                const int sq2 = m * 16 + 4 * lg + r;
                const int jj = (j0 + l15) ^ ((sq2 & 7) << 3);
                Hhi[nxt][sq2][jj] = bf16_rn(hv);
            }
        }

        if (t + 1 < NT) {
            unsigned int p0 = pack_split(xv.x), p1 = pack_split(xv.y);
            *(ushort2*)&Hx[nxt][xs_seq][xd0] = make_ushort2((u16)p0, (u16)p1);
            *(ushort2*)&Hx[nxt][xs_seq][16 + xd0] = make_ushort2((u16)(p0 >> 16), (u16)(p1 >> 16));
        }
        __syncthreads();
    }

    // copy-out (node-major rows n*8+b): final h in Hhi[0]
    for (int ci = tid; ci < 1024; ci += 512) {
        int s = ci >> 4, g16 = ci & 15;
        int sg = g16 ^ (s & 7);
        unsigned int sglob = (unsigned int)(seq0 + s);
        unsigned int b = sglob / NN;
        unsigned int n = sglob - b * NN;
        uint4 v = *(const uint4*)&Hhi[0][s][sg * 8];
        *(uint4*)(hhi_g + ((long)n * 8 + b) * NH + g16 * 8) = v;
    }
}

// ---------- GCN GEMM: out = A @ W^T, single bf16 A plane, bf16 out ----------
__global__ __launch_bounds__(512) void gemmx4_k(
    const u16* __restrict__ Ah, const u16* __restrict__ Whi,
    u16* __restrict__ out)
{
    const int tid = threadIdx.x;
    const int lane = tid & 63;
    const int wid = tid >> 6;
    const int j0 = wid * 16;
    const int l15 = lane & 15;
    const int lg = lane >> 4;
    const long row0 = (long)blockIdx.x * 64;

    short8v Bh[4];
#pragma unroll
    for (int kt = 0; kt < 4; ++kt)
        Bh[kt] = *(const short8v*)(Whi + (j0 + l15) * NH + kt * 32 + 8 * lg);

#pragma unroll
    for (int m = 0; m < 4; ++m) {
        f32x4 acc = (f32x4){0.f, 0.f, 0.f, 0.f};
#pragma unroll
        for (int kt = 0; kt < 4; ++kt) {
            long ar = (row0 + m * 16 + l15) * NH + kt * 32 + 8 * lg;
            short8v ah = *(const short8v*)(Ah + ar);
            acc = __builtin_amdgcn_mfma_f32_16x16x32_bf16(ah, Bh[kt], acc, 0, 0, 0);
        }
#pragma unroll
        for (int r = 0; r < 4; ++r)
            out[(row0 + m * 16 + 4 * lg + r) * NH + j0 + l15] = bf16_rn(acc[r]);
    }
}

// ---------------- degree accumulation ---------------------------------------
__global__ void degacc_k(const int* __restrict__ ei, const float* __restrict__ ew,
                         float* deg, int* cnt) {
    int e = blockIdx.x * 256 + threadIdx.x;
    if (e < NE) {
        int d = ei[NE + e];
        atomicAdd(&deg[d], ew[e]);
        atomicAdd(&cnt[d], 1);
    }
}

// ---------------- scan (+ dinv) ---------------------------------------------
__global__ __launch_bounds__(1024) void scan_k(const int* __restrict__ cnt,
                                               int* __restrict__ rowp,
                                               const float* __restrict__ deg,
                                               float* __restrict__ dinv) {
    for (int idx = threadIdx.x; idx < NN; idx += 1024) {
        float d = deg[idx];
        dinv[idx] = d > 0.f ? rsqrtf(d) : 0.f;
    }
    __shared__ int sA[1024];
    __shared__ int sB[1024];
    const int tid = threadIdx.x;
    const int CH = 10;
    int base = tid * CH;
    int local[CH];
    int ssum = 0;
#pragma unroll
    for (int i = 0; i < CH; ++i) {
        int idx = base + i;
        int v = (idx < NN) ? cnt[idx] : 0;
        local[i] = v; ssum += v;
    }
    int* src = sA; int* dst = sB;
    src[tid] = ssum;
    __syncthreads();
    for (int off = 1; off < 1024; off <<= 1) {
        int v = src[tid];
        if (tid >= off) v += src[tid - off];
        dst[tid] = v;
        __syncthreads();
        int* tmp = src; src = dst; dst = tmp;
    }
    int run = src[tid] - ssum;
#pragma unroll
    for (int i = 0; i < CH; ++i) {
        int idx = base + i;
        if (idx < NN) rowp[idx] = run;
        run += local[i];
    }
    if (tid == 1023) rowp[NN] = src[1023];
}

__global__ void scatter_k(const int* __restrict__ ei, const float* __restrict__ ew,
                          const float* __restrict__ dinv, const int* __restrict__ rowp,
                          int* fill, int* __restrict__ col, float* __restrict__ val)
{
    int e = blockIdx.x * 256 + threadIdx.x;
    if (e >= NE) return;
    int srcn = ei[e], d = ei[NE + e];
    int pos = rowp[d] + atomicAdd(&fill[d], 1);
    col[pos] = srcn;
    val[pos] = dinv[srcn] * ew[e] * dinv[d];
}

// ---------- gather v6: node-major bf16 rows; EMIT=0 -> bf16, 1 -> fused FC --
template<int EMIT>
__global__ __launch_bounds__(256) void gather6_k(const u16* __restrict__ xlb,
    const int* __restrict__ rowp, const int* __restrict__ col,
    const float* __restrict__ val, const float* __restrict__ dinv,
    const float* __restrict__ bias,
    u16* __restrict__ ohi,
    const float* __restrict__ fcw, const float* __restrict__ fcb,
    float* __restrict__ out)
{
    __shared__ float hrow[8][132];
    __shared__ float wl[16][132];
    const int n = blockIdx.x;
    const int tid = threadIdx.x;
    const int q = tid & 31;            // channel-quad (bias index)
    if (EMIT == 1) {
        for (int l = tid; l < 16 * 128; l += 256)
            wl[l >> 7][l & 127] = fcw[l];
    }
    const float dn = dinv[n];
    const float sn = dn * dn;          // self-loop norm
    float4 acc;
    {
        ushort4 u = *(const ushort4*)(xlb + (long)n * 1024 + tid * 4);
        acc.x = sn * bf16f(u.x); acc.y = sn * bf16f(u.y);
        acc.z = sn * bf16f(u.z); acc.w = sn * bf16f(u.w);
    }
    int e = rowp[n];
    const int e1 = rowp[n + 1];
    for (; e + 2 <= e1; e += 2) {      // edge scalars wave-uniform -> s_load
        const int s0 = col[e], s1 = col[e + 1];
        const float w0 = val[e], w1 = val[e + 1];
        const ushort4 u0 = *(const ushort4*)(xlb + (long)s0 * 1024 + tid * 4);
        const ushort4 u1 = *(const ushort4*)(xlb + (long)s1 * 1024 + tid * 4);
        acc.x = fmaf(w0, bf16f(u0.x), acc.x); acc.y = fmaf(w0, bf16f(u0.y), acc.y);
        acc.z = fmaf(w0, bf16f(u0.z), acc.z); acc.w = fmaf(w0, bf16f(u0.w), acc.w);
        acc.x = fmaf(w1, bf16f(u1.x), acc.x); acc.y = fmaf(w1, bf16f(u1.y), acc.y);
        acc.z = fmaf(w1, bf16f(u1.z), acc.z); acc.w = fmaf(w1, bf16f(u1.w), acc.w);
    }
    if (e < e1) {
        const int s0 = col[e];
        const float w0 = val[e];
        const ushort4 u0 = *(const ushort4*)(xlb + (long)s0 * 1024 + tid * 4);
        acc.x = fmaf(w0, bf16f(u0.x), acc.x); acc.y = fmaf(w0, bf16f(u0.y), acc.y);
        acc.z = fmaf(w0, bf16f(u0.z), acc.z); acc.w = fmaf(w0, bf16f(u0.w), acc.w);
    }
    const float4 bb = ((const float4*)bias)[q];
    const float o0 = fmaxf(acc.x + bb.x, 0.f);
    const float o1 = fmaxf(acc.y + bb.y, 0.f);
    const float o2 = fmaxf(acc.z + bb.z, 0.f);
    const float o3 = fmaxf(acc.w + bb.w, 0.f);
    if (EMIT == 0) {
        ushort4 h4 = make_ushort4(bf16_rn(o0), bf16_rn(o1), bf16_rn(o2), bf16_rn(o3));
        *(ushort4*)(ohi + (long)n * 1024 + tid * 4) = h4;
    } else {
        const int b = tid >> 5;
        *(float4*)&hrow[b][q * 4] = make_float4(o0, o1, o2, o3);
        __syncthreads();
        if (tid < 128) {
            const int b2 = tid >> 4, o = tid & 15;
            float a = fcb[o];
#pragma unroll 8
            for (int k = 0; k < NH; ++k) a = fmaf(hrow[b2][k], wl[o][k], a);
            out[((long)b2 * NN + n) * 16 + o] = a;
        }
    }
}

// ---------------------------------------------------------------------------
extern "C" void kernel_launch(void* const* d_in, const int* in_sizes, int n_in,
                              void* d_out, int out_size, void* d_ws, size_t ws_size,
                              hipStream_t stream)
{
    const float* x   = (const float*)d_in[0];
    const int*   ei  = (const int*)d_in[1];
    const float* ew  = (const float*)d_in[2];
    const float* Wih = (const float*)d_in[3];
    const float* Whh = (const float*)d_in[4];
    const float* bih = (const float*)d_in[5];
    const float* bhh = (const float*)d_in[6];
    const float* g1w = (const float*)d_in[7];
    const float* g1b = (const float*)d_in[8];
    const float* g2w = (const float*)d_in[9];
    const float* g2b = (const float*)d_in[10];
    const float* fcw = (const float*)d_in[11];
    const float* fcb = (const float*)d_in[12];
    float* out = (float*)d_out;

    char* ws = (char*)d_ws;
    u16* whh_hi  = (u16*)(ws + 0);           // 131072
    u16* wih_hi2 = (u16*)(ws + 131072);      // 32768
    u16* g1hi    = (u16*)(ws + 196608);      // 32768
    u16* g2hi    = (u16*)(ws + 229376);      // 32768
    float* deg   = (float*)(ws + 262144);
    float* dinv  = (float*)(ws + 303104);
    int*   cnt   = (int*)(ws + 344064);
    int*   fill  = (int*)(ws + 385024);
    int*   rowp  = (int*)(ws + 425984);
    int*   col   = (int*)(ws + 466176);      // 640000
    float* val   = (float*)(ws + 1106176);   // 640000
    u16* hhi     = (u16*)(ws + 2097152);     // 20480000 (node-major bf16)
    u16* xlb     = (u16*)(ws + 22577152);    // 20480000 (node-major bf16)

    prep_w_k<<<256, 256, 0, stream>>>(Whh, Wih, g1w, g2w, whh_hi, wih_hi2,
                                      g1hi, g2hi, deg, cnt, fill);
    lstm4d_k<<<BN / 64, 512, 0, stream>>>(x, whh_hi, wih_hi2, bih, bhh, hhi);

    degacc_k<<<(NE + 255) / 256, 256, 0, stream>>>(ei, ew, deg, cnt);
    scan_k<<<1, 1024, 0, stream>>>(cnt, rowp, deg, dinv);
    scatter_k<<<(NE + 255) / 256, 256, 0, stream>>>(ei, ew, dinv, rowp, fill, col, val);

    gemmx4_k<<<BN / 64, 512, 0, stream>>>(hhi, g1hi, xlb);
    gather6_k<0><<<NN, 256, 0, stream>>>(xlb, rowp, col, val, dinv, g1b,
                                         hhi, nullptr, nullptr, nullptr);
    gemmx4_k<<<BN / 64, 512, 0, stream>>>(hhi, g2hi, xlb);
    gather6_k<1><<<NN, 256, 0, stream>>>(xlb, rowp, col, val, dinv, g2b,
                                         nullptr, fcw, fcb, out);
}